// Round 7
// baseline (568.023 us; speedup 1.0000x reference)
//
#include <hip/hip_runtime.h>
#include <hip/hip_bf16.h>

typedef __attribute__((ext_vector_type(8))) short short8;
typedef __attribute__((ext_vector_type(4))) short short4v;
typedef __attribute__((ext_vector_type(4))) float floatx4;

#define TDIM 2048
#define BDIM 2
#define MROWS (BDIM * TDIM)   // 4096

#define ASM_VMCNT0() __asm__ volatile("s_waitcnt vmcnt(0)" ::: "memory")
#define ASM_LGKM0()  __asm__ volatile("s_waitcnt lgkmcnt(0)" ::: "memory")
#define ASM_BARRIER() __asm__ volatile("s_barrier" ::: "memory")

// K=16 bf16 MFMA wrapper (host pass must not see device-only builtins).
__device__ __forceinline__ floatx4 mfma16(short4v a, short4v b, floatx4 c) {
#if defined(__HIP_DEVICE_COMPILE__)
#if __has_builtin(__builtin_amdgcn_mfma_f32_16x16x16bf16_1k)
    return __builtin_amdgcn_mfma_f32_16x16x16bf16_1k(a, b, c, 0, 0, 0);
#else
    short8 az = {a[0], a[1], a[2], a[3], 0, 0, 0, 0};
    short8 bz = {b[0], b[1], b[2], b[3], 0, 0, 0, 0};
    return __builtin_amdgcn_mfma_f32_16x16x32_bf16(az, bz, c, 0, 0, 0);
#endif
#else
    (void)a; (void)b;
    return c;
#endif
}

// async global->LDS, 16B per lane; LDS dest = wave-uniform base + lane*16
__device__ __forceinline__ void gload_lds16(const void* g, void* l) {
    __builtin_amdgcn_global_load_lds((const __attribute__((address_space(1))) void*)g,
                                     (__attribute__((address_space(3))) void*)l, 16, 0, 0);
}

__device__ __forceinline__ short bf16s(float x) {
    __hip_bfloat16 h = __float2bfloat16(x);
    return *(short*)&h;
}

// packed 4x f32 -> short4v of bf16 (maps to v_cvt_pk_bf16_f32 when available)
__device__ __forceinline__ short4v pk4(float a, float b, float c, float d) {
    union { __hip_bfloat162 h2[2]; short4v s4; } u;
    u.h2[0] = __float22bfloat162_rn(make_float2(a, b));
    u.h2[1] = __float22bfloat162_rn(make_float2(c, d));
    return u.s4;
}

// ---------------------------------------------------------------------------
// fused dual cast fp32 -> bf16 (dec then enc), 4 elems/thread
__global__ __launch_bounds__(256) void cast2_k(const float* __restrict__ a,
                                               const float* __restrict__ b,
                                               __hip_bfloat16* __restrict__ oa,
                                               __hip_bfloat16* __restrict__ ob) {
    const int blk = blockIdx.x;
    const float* in = (blk < 4096) ? a : b;
    __hip_bfloat16* out = (blk < 4096) ? oa : ob;
    const size_t base = (size_t)(blk & 4095) * 1024 + threadIdx.x * 4;
    float4 v = *(const float4*)&in[base];
    *(short4v*)&out[base] = pk4(v.x, v.y, v.z, v.w);
}

// 32x32 transpose-cast tile helper
__device__ __forceinline__ void t32(float (*tile)[33], const float* __restrict__ in,
                                    __hip_bfloat16* __restrict__ out, int R, int C,
                                    int c0, int r0) {
    const int tx = threadIdx.x & 31, ty = threadIdx.x >> 5;
#pragma unroll
    for (int i = 0; i < 4; ++i)
        tile[ty + 8 * i][tx] = in[(size_t)(r0 + ty + 8 * i) * C + c0 + tx];
    __syncthreads();
#pragma unroll
    for (int i = 0; i < 4; ++i)
        out[(size_t)(c0 + ty + 8 * i) * R + r0 + tx] = __float2bfloat16(tile[tx][ty + 8 * i]);
}

// One fused kernel for ALL weight prep: 10 transposes + 2 bias concats.
__global__ __launch_bounds__(256) void prep_w_k(
    const float* __restrict__ Wq_s, const float* __restrict__ Wk_s, const float* __restrict__ Wv_s,
    const float* __restrict__ Wq_c, const float* __restrict__ Wk_c, const float* __restrict__ Wv_c,
    const float* __restrict__ Wo_s, const float* __restrict__ Wo_c,
    const float* __restrict__ W1, const float* __restrict__ W2,
    const float* __restrict__ bq_s, const float* __restrict__ bk_s, const float* __restrict__ bv_s,
    const float* __restrict__ bk_c, const float* __restrict__ bv_c,
    __hip_bfloat16* __restrict__ WtQKVs, __hip_bfloat16* __restrict__ WtQc,
    __hip_bfloat16* __restrict__ WtKVc, __hip_bfloat16* __restrict__ WtOs,
    __hip_bfloat16* __restrict__ WtOc, __hip_bfloat16* __restrict__ Wt1,
    __hip_bfloat16* __restrict__ Wt2,
    float* __restrict__ BiasQKVs, float* __restrict__ BiasKVc) {
    __shared__ float tile[32][33];
    const int t = blockIdx.x;
    if (t < 6144) {  // per-head stacks: R=1024, C=64, 16 slabs, 64 tiles/slab
        const int seg = t >> 10, tl = t & 1023;
        const float* s;
        __hip_bfloat16* d;
        if (seg == 0) { s = Wq_s; d = WtQKVs; }
        else if (seg == 1) { s = Wk_s; d = WtQKVs + 1048576; }
        else if (seg == 2) { s = Wv_s; d = WtQKVs + 2097152; }
        else if (seg == 3) { s = Wq_c; d = WtQc; }
        else if (seg == 4) { s = Wk_c; d = WtKVc; }
        else { s = Wv_c; d = WtKVc + 1048576; }
        const int slab = tl >> 6, rem = tl & 63;
        t32(tile, s + (size_t)slab * 65536, d + (size_t)slab * 65536, 1024, 64,
            (rem & 1) * 32, (rem >> 1) * 32);
    } else if (t < 8192) {  // Wo_s / Wo_c: 1024x1024
        const int rem = (t - 6144) & 1023;
        const float* s = (t < 7168) ? Wo_s : Wo_c;
        __hip_bfloat16* d = (t < 7168) ? WtOs : WtOc;
        t32(tile, s, d, 1024, 1024, (rem & 31) * 32, (rem >> 5) * 32);
    } else if (t < 12288) {  // W1: R=1024 C=4096
        const int rem = t - 8192;
        t32(tile, W1, Wt1, 1024, 4096, (rem & 127) * 32, (rem >> 7) * 32);
    } else if (t < 16384) {  // W2: R=4096 C=1024
        const int rem = t - 12288;
        t32(tile, W2, Wt2, 4096, 1024, (rem & 31) * 32, (rem >> 5) * 32);
    } else if (t < 16396) {  // concat3 -> BiasQKVs
        const int i = (t - 16384) * 256 + threadIdx.x;
        BiasQKVs[i] = (i < 1024) ? bq_s[i] : (i < 2048 ? bk_s[i - 1024] : bv_s[i - 2048]);
    } else {  // concat2 -> BiasKVc
        const int i = (t - 16396) * 256 + threadIdx.x;
        BiasKVc[i] = (i < 1024) ? bk_c[i] : bv_c[i - 1024];
    }
}

// ---------------------------------------------------------------------------
// Pipelined bf16 MFMA GEMM core: 128x128 tile, BK=64, double-buffered LDS,
// XOR-swizzled tiles (granule g of row r stored at g^(r&7)) -> conflict-free.
__device__ __forceinline__ void gemm_core(
    const __hip_bfloat16* __restrict__ A, const __hip_bfloat16* __restrict__ Bt,
    int K, int kBeg, int kLen,
    const float* __restrict__ bias, __hip_bfloat16* __restrict__ C, int ldc,
    float* __restrict__ Pf,
    __hip_bfloat16* __restrict__ Vt, int vt_col0, int relu,
    int m0, int n0, __hip_bfloat16* sm) {
    const int tid = threadIdx.x;
    const int lane = tid & 63, wave = tid >> 6;
    const int quad = lane >> 4, l16 = lane & 15;
    const int wm = (wave >> 1) * 64, wn = (wave & 1) * 64;
    const int lrow = lane >> 3;
    const int gsw = (((lane & 7) ^ lrow)) * 8;  // swizzled source column (elems)
    const int sw7 = l16 & 7;                    // reader swizzle key (row&7)
    const __hip_bfloat16* gA = A + (size_t)(m0 + wave * 32 + lrow) * K + kBeg + gsw;
    const __hip_bfloat16* gB = Bt + (size_t)(n0 + wave * 32 + lrow) * K + kBeg + gsw;
    __hip_bfloat16* lA = sm + wave * 2048;
    __hip_bfloat16* lB = sm + 16384 + wave * 2048;
    floatx4 acc[4][4] = {};
    const int T = kLen >> 6;
#pragma unroll
    for (int i = 0; i < 4; ++i) {
        gload_lds16(gA + (size_t)i * 8 * K, lA + i * 512);
        gload_lds16(gB + (size_t)i * 8 * K, lB + i * 512);
    }
    for (int t = 0; t < T; ++t) {
        ASM_VMCNT0();
        ASM_BARRIER();
        if (t + 1 < T) {
            const int koff = (t + 1) << 6;
            const int b = ((t + 1) & 1) * 8192;
#pragma unroll
            for (int i = 0; i < 4; ++i) {
                gload_lds16(gA + (size_t)i * 8 * K + koff, lA + b + i * 512);
                gload_lds16(gB + (size_t)i * 8 * K + koff, lB + b + i * 512);
            }
        }
        const __hip_bfloat16* cA = sm + (t & 1) * 8192;
        const __hip_bfloat16* cB = sm + 16384 + (t & 1) * 8192;
#pragma unroll
        for (int kc = 0; kc < 2; ++kc) {
            short8 af[4], bfr[4];
#pragma unroll
            for (int i = 0; i < 4; ++i) {
                af[i] = *(const short8*)&cA[(wm + i * 16 + l16) * 64 +
                                            (((kc * 4 + quad) ^ sw7) * 8)];
                bfr[i] = *(const short8*)&cB[(wn + i * 16 + l16) * 64 +
                                             (((kc * 4 + quad) ^ sw7) * 8)];
            }
#pragma unroll
            for (int mi = 0; mi < 4; ++mi)
#pragma unroll
                for (int ni = 0; ni < 4; ++ni)
                    acc[mi][ni] =
                        __builtin_amdgcn_mfma_f32_16x16x32_bf16(af[mi], bfr[ni], acc[mi][ni], 0, 0, 0);
        }
    }
    // epilogue
    if (Pf) {
#pragma unroll
        for (int ni = 0; ni < 4; ++ni) {
            const int col = n0 + wn + ni * 16 + l16;
#pragma unroll
            for (int mi = 0; mi < 4; ++mi)
#pragma unroll
                for (int r = 0; r < 4; ++r) {
                    const int row = m0 + wm + mi * 16 + quad * 4 + r;
                    Pf[(size_t)row * ldc + col] = acc[mi][ni][r];
                }
        }
    } else {
        const bool toVt = (n0 >= vt_col0);
#pragma unroll
        for (int ni = 0; ni < 4; ++ni) {
            const int col = n0 + wn + ni * 16 + l16;
            const float bv = bias[col];
#pragma unroll
            for (int mi = 0; mi < 4; ++mi) {
                const int row0 = m0 + wm + mi * 16 + quad * 4;
                if (toVt) {
                    const int b = row0 >> 11, t0 = row0 & (TDIM - 1);
                    *(short4v*)&Vt[((size_t)(b * 1024 + (col - vt_col0)) << 11) + t0] =
                        pk4(acc[mi][ni][0] + bv, acc[mi][ni][1] + bv,
                            acc[mi][ni][2] + bv, acc[mi][ni][3] + bv);
                } else {
#pragma unroll
                    for (int r = 0; r < 4; ++r) {
                        float v = acc[mi][ni][r] + bv;
                        if (relu) v = fmaxf(v, 0.f);
                        C[(size_t)(row0 + r) * ldc + col] = __float2bfloat16(v);
                    }
                }
            }
        }
    }
}

__global__ __launch_bounds__(256) void gemm_bf16_k(const __hip_bfloat16* __restrict__ A,
                                                   const __hip_bfloat16* __restrict__ Bt,
                                                   const float* __restrict__ bias,
                                                   __hip_bfloat16* __restrict__ C,
                                                   int N, int K, int relu,
                                                   __hip_bfloat16* __restrict__ Vt, int vt_col0) {
    __shared__ __hip_bfloat16 sm[2 * 128 * 64 * 2];
    gemm_core(A, Bt, K, 0, K, bias, C, N, nullptr, Vt, vt_col0, relu,
              blockIdx.y * 128, blockIdx.x * 128, sm);
}

__global__ __launch_bounds__(256) void gemm_sk2_k(const __hip_bfloat16* __restrict__ A,
                                                  const __hip_bfloat16* __restrict__ Bt,
                                                  float* __restrict__ Pf, int N, int K) {
    __shared__ __hip_bfloat16 sm[2 * 128 * 64 * 2];
    const int z = blockIdx.z;
    gemm_core(A, Bt, K, z * (K >> 1), K >> 1, nullptr, nullptr, N,
              Pf + (size_t)z * MROWS * N, nullptr, 1 << 30, 0,
              blockIdx.y * 128, blockIdx.x * 128, sm);
}

__global__ __launch_bounds__(256) void gemm_pair_k(
    const __hip_bfloat16* __restrict__ A1, const __hip_bfloat16* __restrict__ Bt1,
    const float* __restrict__ bias1, __hip_bfloat16* __restrict__ C1, int N1, int K1,
    const __hip_bfloat16* __restrict__ A2, const __hip_bfloat16* __restrict__ Bt2,
    const float* __restrict__ bias2, __hip_bfloat16* __restrict__ C2, int N2, int K2,
    __hip_bfloat16* __restrict__ Vt2, int vtc2, int nx1) {
    __shared__ __hip_bfloat16 sm[2 * 128 * 64 * 2];
    if ((int)blockIdx.x < nx1)
        gemm_core(A1, Bt1, K1, 0, K1, bias1, C1, N1, nullptr, nullptr, 1 << 30, 0,
                  blockIdx.y * 128, blockIdx.x * 128, sm);
    else
        gemm_core(A2, Bt2, K2, 0, K2, bias2, C2, N2, nullptr, Vt2, vtc2, 0,
                  blockIdx.y * 128, (blockIdx.x - nx1) * 128, sm);
}

// ---------------------------------------------------------------------------
// Flash attention, TWO Q-tiles per block sharing one K/V stream.
// S^T = K·Q^T (register-resident P as K=16 PV B-fragment), no LDS round-trip.
// K-frag reads, sV reads, DMA and barriers amortized over both tiles.
__device__ __forceinline__ void flash_two(
    const __hip_bfloat16* __restrict__ Q, int ldq, int qc0,
    const __hip_bfloat16* __restrict__ Kp, int ldk,
    const __hip_bfloat16* __restrict__ Vp,
    __hip_bfloat16* __restrict__ O, int causal, int q0a, int q0b,
    size_t rowb, int h, __hip_bfloat16* sK, __hip_bfloat16* sV) {
    const int tid = threadIdx.x, lane = tid & 63, wave = tid >> 6;
    const int quad = lane >> 4, l16 = lane & 15;
    const int lrow = lane >> 3;
    const int gsw = ((lane & 7) ^ lrow) * 8;  // DMA swizzled source col (elems)
    const int sw7 = l16 & 7;
    const float qs = 0.18033688f;  // 0.125 * log2(e)
    short8 qfA[2], qfB[2];
    {
        const __hip_bfloat16* qpA = Q + (rowb + q0a + wave * 16 + l16) * (size_t)ldq + qc0 + h * 64;
        const __hip_bfloat16* qpB = Q + (rowb + q0b + wave * 16 + l16) * (size_t)ldq + qc0 + h * 64;
#pragma unroll
        for (int half = 0; half < 2; ++half) {
            short8 ra = *(const short8*)(qpA + half * 32 + quad * 8);
            short8 rb = *(const short8*)(qpB + half * 32 + quad * 8);
#pragma unroll
            for (int j = 0; j < 8; ++j) {
                qfA[half][j] = bf16s(__uint_as_float(((unsigned)(unsigned short)ra[j]) << 16) * qs);
                qfB[half][j] = bf16s(__uint_as_float(((unsigned)(unsigned short)rb[j]) << 16) * qs);
            }
        }
    }
    short4v ones4;
#pragma unroll
    for (int j = 0; j < 4; ++j) ones4[j] = (short)0x3F80;  // bf16 1.0
    floatx4 OtA[4] = {}, OtB[4] = {};
    floatx4 acclA = {}, acclB = {};
    const int TQ = TDIM >> 6;
    const int lastA = causal ? (q0a >> 6) : TQ - 1;
    const int lastB = causal ? (q0b >> 6) : TQ - 1;
    const int lastT = (lastA > lastB) ? lastA : lastB;
    ASM_LGKM0();
    ASM_BARRIER();
#pragma unroll
    for (int i = 0; i < 2; ++i) {
        const int rb = wave * 16 + i * 8;
        gload_lds16(&Kp[(rowb + rb + lrow) * (size_t)ldk + gsw], &sK[rb * 64]);
        gload_lds16(&Vp[(size_t)(rb + lrow) * TDIM + gsw], &sV[rb * 64]);
    }
    for (int t = 0; t <= lastT; ++t) {
        ASM_VMCNT0();
        ASM_BARRIER();
        if (t < lastT) {
            const int s1 = (t + 1) << 6, nb = ((t + 1) & 1) * 4096;
#pragma unroll
            for (int i = 0; i < 2; ++i) {
                const int rb = wave * 16 + i * 8;
                gload_lds16(&Kp[(rowb + s1 + rb + lrow) * (size_t)ldk + gsw], &sK[nb + rb * 64]);
                gload_lds16(&Vp[(size_t)(rb + lrow) * TDIM + s1 + gsw], &sV[nb + rb * 64]);
            }
        }
        const int cb = (t & 1) * 4096;
        const bool actA = (t <= lastA), actB = (t <= lastB);
        floatx4 SfA[4] = {}, SfB[4] = {};
#pragma unroll
        for (int st = 0; st < 4; ++st) {
            short8 b0 = *(const short8*)&sK[cb + (st * 16 + l16) * 64 + ((quad ^ sw7) * 8)];
            short8 b1 = *(const short8*)&sK[cb + (st * 16 + l16) * 64 + (((4 + quad) ^ sw7) * 8)];
            if (actA) {
                SfA[st] = __builtin_amdgcn_mfma_f32_16x16x32_bf16(b0, qfA[0], SfA[st], 0, 0, 0);
                SfA[st] = __builtin_amdgcn_mfma_f32_16x16x32_bf16(b1, qfA[1], SfA[st], 0, 0, 0);
            }
            if (actB) {
                SfB[st] = __builtin_amdgcn_mfma_f32_16x16x32_bf16(b0, qfB[0], SfB[st], 0, 0, 0);
                SfB[st] = __builtin_amdgcn_mfma_f32_16x16x32_bf16(b1, qfB[1], SfB[st], 0, 0, 0);
            }
        }
        short4v pfA[4], pfB[4];
        const int qr = wave * 16 + l16;
        if (actA) {
#pragma unroll
            for (int st = 0; st < 4; ++st) {
#pragma unroll
                for (int r = 0; r < 4; ++r) SfA[st][r] = exp2f(SfA[st][r]);
                if (causal && t == lastA) {
#pragma unroll
                    for (int r = 0; r < 4; ++r)
                        if (st * 16 + quad * 4 + r > qr) SfA[st][r] = 0.f;
                }
                pfA[st] = pk4(SfA[st][0], SfA[st][1], SfA[st][2], SfA[st][3]);
                acclA = mfma16(ones4, pfA[st], acclA);
            }
        }
        if (actB) {
#pragma unroll
            for (int st = 0; st < 4; ++st) {
#pragma unroll
                for (int r = 0; r < 4; ++r) SfB[st][r] = exp2f(SfB[st][r]);
                if (causal && t == lastB) {
#pragma unroll
                    for (int r = 0; r < 4; ++r)
                        if (st * 16 + quad * 4 + r > qr) SfB[st][r] = 0.f;
                }
                pfB[st] = pk4(SfB[st][0], SfB[st][1], SfB[st][2], SfB[st][3]);
                acclB = mfma16(ones4, pfB[st], acclB);
            }
        }
#pragma unroll
        for (int dt = 0; dt < 4; ++dt)
#pragma unroll
            for (int st = 0; st < 4; ++st) {
                short4v av = *(const short4v*)&sV[cb + (dt * 16 + l16) * 64 +
                                                 (((st * 2 + (quad >> 1)) ^ sw7) * 8) +
                                                 (quad & 1) * 4];
                if (actA) OtA[dt] = mfma16(av, pfA[st], OtA[dt]);
                if (actB) OtB[dt] = mfma16(av, pfB[st], OtB[dt]);
            }
    }
    const float invA = 1.0f / acclA[0], invB = 1.0f / acclB[0];
    __hip_bfloat16* opA = O + (rowb + q0a + wave * 16 + l16) * (size_t)1024 + h * 64 + quad * 4;
    __hip_bfloat16* opB = O + (rowb + q0b + wave * 16 + l16) * (size_t)1024 + h * 64 + quad * 4;
#pragma unroll
    for (int dt = 0; dt < 4; ++dt) {
        *(short4v*)(opA + dt * 16) = pk4(OtA[dt][0] * invA, OtA[dt][1] * invA,
                                         OtA[dt][2] * invA, OtA[dt][3] * invA);
        *(short4v*)(opB + dt * 16) = pk4(OtB[dt][0] * invB, OtB[dt][1] * invB,
                                         OtB[dt][2] * invB, OtB[dt][3] * invB);
    }
}

// grid (16, 32). causal=1: tiles {bx, 31-bx}; causal=0: tiles {bx, bx+16}.
__global__ __launch_bounds__(256) void flash_attn(const __hip_bfloat16* __restrict__ Q, int ldq, int qc0,
                                                  const __hip_bfloat16* __restrict__ K, int ldk, int kc0,
                                                  const __hip_bfloat16* __restrict__ Vt,
                                                  __hip_bfloat16* __restrict__ O, int causal) {
    __shared__ __hip_bfloat16 sK[2 * 64 * 64];
    __shared__ __hip_bfloat16 sV[2 * 64 * 64];
    const int bh = blockIdx.y, b = bh >> 4, h = bh & 15;
    const size_t rowb = (size_t)b * TDIM;
    const __hip_bfloat16* Kp = K + kc0 + h * 64;
    const __hip_bfloat16* Vp = Vt + ((size_t)(b * 1024 + h * 64) << 11);
    const int bx = blockIdx.x;
    const int q0a = bx * 64;
    const int q0b = causal ? (31 - bx) * 64 : (bx + 16) * 64;
    flash_two(Q, ldq, qc0, Kp, ldk, Vp, O, causal, q0a, q0b, rowb, h, sK, sV);
}

// ---------------------------------------------------------------------------
// LayerNorm with fused split-K reduction: delta = d0 + d1 + biasN.
__global__ __launch_bounds__(256) void ln2_k(const float* __restrict__ resid,
                                             const float* __restrict__ d0,
                                             const float* __restrict__ d1,
                                             const float* __restrict__ biasN,
                                             const float* __restrict__ gamma,
                                             const float* __restrict__ beta,
                                             float* __restrict__ outf,
                                             __hip_bfloat16* __restrict__ outb) {
    const int row = blockIdx.x, tid = threadIdx.x;
    const size_t base = (size_t)row * 1024;
    float x[4], s = 0.f, sq = 0.f;
#pragma unroll
    for (int i = 0; i < 4; ++i) {
        const int c = tid + 256 * i;
        x[i] = resid[base + c] + d0[base + c] + d1[base + c] + biasN[c];
        s += x[i];
        sq += x[i] * x[i];
    }
#pragma unroll
    for (int off = 32; off > 0; off >>= 1) {
        s += __shfl_down(s, off);
        sq += __shfl_down(sq, off);
    }
    __shared__ float red[8];
    if ((tid & 63) == 0) {
        red[tid >> 6] = s;
        red[4 + (tid >> 6)] = sq;
    }
    __syncthreads();
    const float S = red[0] + red[1] + red[2] + red[3];
    const float Q2 = red[4] + red[5] + red[6] + red[7];
    const float mean = S * (1.f / 1024.f);
    const float var = Q2 * (1.f / 1024.f) - mean * mean;
    const float rstd = rsqrtf(var + 1e-5f);
#pragma unroll
    for (int i = 0; i < 4; ++i) {
        const int c = tid + 256 * i;
        const float y = (x[i] - mean) * rstd * gamma[c] + beta[c];
        outf[base + c] = y;
        outb[base + c] = __float2bfloat16(y);
    }
}

// ---------------------------------------------------------------------------
extern "C" void kernel_launch(void* const* d_in, const int* in_sizes, int n_in,
                              void* d_out, int out_size, void* d_ws, size_t ws_size,
                              hipStream_t stream) {
    (void)in_sizes; (void)n_in; (void)out_size; (void)ws_size;
    const float* dec  = (const float*)d_in[0];
    const float* enc  = (const float*)d_in[1];
    const float* Wq_s = (const float*)d_in[2];
    const float* bq_s = (const float*)d_in[3];
    const float* Wk_s = (const float*)d_in[4];
    const float* bk_s = (const float*)d_in[5];
    const float* Wv_s = (const float*)d_in[6];
    const float* bv_s = (const float*)d_in[7];
    const float* Wo_s = (const float*)d_in[8];
    const float* bo_s = (const float*)d_in[9];
    const float* Wq_c = (const float*)d_in[10];
    const float* bq_c = (const float*)d_in[11];
    const float* Wk_c = (const float*)d_in[12];
    const float* bk_c = (const float*)d_in[13];
    const float* Wv_c = (const float*)d_in[14];
    const float* bv_c = (const float*)d_in[15];
    const float* Wo_c = (const float*)d_in[16];
    const float* bo_c = (const float*)d_in[17];
    const float* W1   = (const float*)d_in[18];
    const float* b1   = (const float*)d_in[19];
    const float* W2   = (const float*)d_in[20];
    const float* b2   = (const float*)d_in[21];
    const float* g1   = (const float*)d_in[22];
    const float* be1  = (const float*)d_in[23];
    const float* g2   = (const float*)d_in[24];
    const float* be2  = (const float*)d_in[25];
    const float* g3   = (const float*)d_in[26];
    const float* be3  = (const float*)d_in[27];

    char* w = (char*)d_ws;
    const size_t MB = 1ull << 20;
    __hip_bfloat16* Xdec   = (__hip_bfloat16*)(w + 0 * MB);    // 8 MB
    __hip_bfloat16* Xenc   = (__hip_bfloat16*)(w + 8 * MB);    // 8 MB
    __hip_bfloat16* WtQKVs = (__hip_bfloat16*)(w + 16 * MB);   // 6 MB  [3072][1024]
    __hip_bfloat16* WtOs   = (__hip_bfloat16*)(w + 22 * MB);   // 2 MB
    __hip_bfloat16* WtQc   = (__hip_bfloat16*)(w + 24 * MB);   // 2 MB
    __hip_bfloat16* WtKVc  = (__hip_bfloat16*)(w + 26 * MB);   // 4 MB  [2048][1024]
    __hip_bfloat16* WtOc   = (__hip_bfloat16*)(w + 30 * MB);   // 2 MB
    __hip_bfloat16* Wt1    = (__hip_bfloat16*)(w + 32 * MB);   // 8 MB  [4096][1024]
    __hip_bfloat16* Wt2    = (__hip_bfloat16*)(w + 40 * MB);   // 8 MB  [1024][4096]
    float*          BiasQKVs = (float*)(w + 48 * MB);          // 12 KB
    float*          BiasKVc  = (float*)(w + 48 * MB + 65536);  // 8 KB
    __hip_bfloat16* QKV    = (__hip_bfloat16*)(w + 49 * MB);   // 24 MB
    __hip_bfloat16* Qc     = QKV;                               // 8 MB [4096][1024]
    __hip_bfloat16* KVc    = (__hip_bfloat16*)(w + 57 * MB);   // 16 MB [4096][2048]
    float*          Psplit = (float*)(w + 49 * MB);            // 32 MB [2][4096][1024]
    __hip_bfloat16* VtBuf  = (__hip_bfloat16*)(w + 73 * MB);   // 8 MB [2048][2048]
    __hip_bfloat16* Attn   = (__hip_bfloat16*)(w + 81 * MB);   // 8 MB
    float*          X1f    = (float*)(w + 97 * MB);            // 16 MB
    __hip_bfloat16* X1b    = (__hip_bfloat16*)(w + 113 * MB);  // 8 MB
    float*          X2f    = (float*)(w + 121 * MB);           // 16 MB
    __hip_bfloat16* X2b    = (__hip_bfloat16*)(w + 137 * MB);  // 8 MB
    __hip_bfloat16* H1     = (__hip_bfloat16*)(w + 145 * MB);  // 32 MB
    float*          P0     = Psplit;
    float*          P1     = Psplit + (size_t)MROWS * 1024;
    const int NOVT = 1 << 30;

    // ---- prep (2 launches) ----
    cast2_k<<<8192, 256, 0, stream>>>(dec, enc, Xdec, Xenc);
    prep_w_k<<<16404, 256, 0, stream>>>(Wq_s, Wk_s, Wv_s, Wq_c, Wk_c, Wv_c, Wo_s, Wo_c,
                                        W1, W2, bq_s, bk_s, bv_s, bk_c, bv_c,
                                        WtQKVs, WtQc, WtKVc, WtOs, WtOc, Wt1, Wt2,
                                        BiasQKVs, BiasKVc);

    // ---- self attention ----
    gemm_bf16_k<<<dim3(24, 32), 256, 0, stream>>>(Xdec, WtQKVs, BiasQKVs, QKV, 3072, 1024, 0,
                                                  VtBuf, 2048);
    flash_attn<<<dim3(16, 32), 256, 0, stream>>>(QKV, 3072, 0, QKV, 3072, 1024, VtBuf, Attn, 1);
    gemm_sk2_k<<<dim3(8, 32, 2), 256, 0, stream>>>(Attn, WtOs, Psplit, 1024, 1024);
    ln2_k<<<MROWS, 256, 0, stream>>>(dec, P0, P1, bo_s, g1, be1, X1f, X1b);

    // ---- cross attention ----
    gemm_pair_k<<<dim3(24, 32), 256, 0, stream>>>(X1b, WtQc, bq_c, Qc, 1024, 1024,
                                                  Xenc, WtKVc, BiasKVc, KVc, 2048, 1024,
                                                  VtBuf, 1024, 8);
    flash_attn<<<dim3(16, 32), 256, 0, stream>>>(Qc, 1024, 0, KVc, 2048, 0, VtBuf, Attn, 0);
    gemm_sk2_k<<<dim3(8, 32, 2), 256, 0, stream>>>(Attn, WtOc, Psplit, 1024, 1024);
    ln2_k<<<MROWS, 256, 0, stream>>>(X1f, P0, P1, bo_c, g2, be2, X2f, X2b);

    // ---- FFN ----
    gemm_bf16_k<<<dim3(32, 32), 256, 0, stream>>>(X2b, Wt1, b1, H1, 4096, 1024, 1,
                                                  (__hip_bfloat16*)nullptr, NOVT);
    gemm_sk2_k<<<dim3(8, 32, 2), 256, 0, stream>>>(H1, Wt2, Psplit, 1024, 4096);
    ln2_k<<<MROWS, 256, 0, stream>>>(X2f, P0, P1, b2, g3, be3, (float*)d_out, X1b);
}